// Round 2
// baseline (176.574 us; speedup 1.0000x reference)
//
#include <hip/hip_runtime.h>

// AnalyticalBoundedLineAttractor — exact linear-regime stepping via Taylor
// recurrence:
//   z = Wx + b; m_dt = (z>0)?dt:0
//   w1 = m_dt*z - dt*x;  wk = (m_dt*(W w) - dt*w)/k;  x+ = x + sum wk
// ||Z|| <= dt*(||W||_2+1) ~ 0.15 -> K=3 terms, local truncation ~2e-5/step,
// accumulated ~6e-3 (threshold 7.7e-2; non-expansive dynamics, no blowup).
//
// R1: broadcast via LDS instead of v_readlane.
//   R0 counters: 65.5 us dispatch vs ~33 us VALU-issue floor -> ~260 cyc
//   stall/matvec, attributable to readlane (VALU->SGPR->VALU hazard wait
//   states, and/or slow transposed-VGPR-file readlane issue). New matvec:
//   lane writes w_i to LDS (ds_write_b32, 2-way alias = free), lgkmcnt(0),
//   then 16x ds_read_b128 at WAVE-UNIFORM addresses (same-address broadcast,
//   conflict-free, 4 vals/instr) feeding 64 FMAs. 81 instr/matvec vs 128,
//   zero readlanes, zero SGPR hazards. FMA grouping/order identical to R0
//   -> bitwise-identical numerics (absmax 0.015625).
//   WAR on wbuf needs no barrier: the next ds_write is data-dependent (via
//   z) on all 16 reads having returned their data.

#define DT_F 0.05f
#define T_STEPS 100
#define DD 64
#define KT 3  // Taylor terms w_1..w_KT
#define BATCH_MAX 256

__device__ __forceinline__ float matvec_lds(const float (&Wr)[DD],
                                            const float* __restrict__ wbuf) {
    float a0 = 0.f, a1 = 0.f, a2 = 0.f, a3 = 0.f;
#pragma unroll
    for (int j = 0; j < DD; j += 4) {
        // Wave-uniform address -> LDS broadcast read, no bank conflict.
        const float4 s = *reinterpret_cast<const float4*>(wbuf + j);
        a0 = fmaf(Wr[j + 0], s.x, a0);
        a1 = fmaf(Wr[j + 1], s.y, a1);
        a2 = fmaf(Wr[j + 2], s.z, a2);
        a3 = fmaf(Wr[j + 3], s.w, a3);
    }
    return (a0 + a1) + (a2 + a3);
}

// Publish this lane's element of the broadcast vector and make it visible.
// Explicit lgkmcnt(0) instead of __syncthreads(): a full barrier would also
// drain vmcnt(0), dragging the per-step trajectory store onto the critical
// path (~300+ cyc/step). "memory" clobber keeps the ds_write above and the
// ds_reads below the wait.
#define PUBLISH(buf, lane, val)                                   \
    do {                                                          \
        (buf)[(lane)] = (val);                                    \
        asm volatile("s_waitcnt lgkmcnt(0)" ::: "memory");        \
    } while (0)

__global__ __launch_bounds__(64, 1)
void abla_kernel(const float* __restrict__ x0,
                 const float* __restrict__ W,
                 const float* __restrict__ bvec,
                 float* __restrict__ out) {
    const int batch = blockIdx.x;
    const int lane = threadIdx.x;

    __shared__ float wbuf[DD];

    // Lane i caches row i of W (natural order) in 64 VGPRs. One-time load;
    // stride-256B across lanes is uncoalesced but only ~147 KB total fetch.
    float Wr[DD];
#pragma unroll
    for (int j = 0; j < DD; j += 4) {
        const float4 w4 = *reinterpret_cast<const float4*>(W + lane * DD + j);
        Wr[j + 0] = w4.x; Wr[j + 1] = w4.y; Wr[j + 2] = w4.z; Wr[j + 3] = w4.w;
    }
    const float bi = bvec[lane];
    float x = x0[batch * DD + lane];
    float* outp = out + (size_t)batch * T_STEPS * DD + lane;

    for (int t = 0; t < T_STEPS; ++t) {
        // Trajectory stores the state BEFORE the update (off critical path).
        outp[(size_t)t * DD] = x;

        // term 1: z = Wx + b gives the regime mask
        PUBLISH(wbuf, lane, x);
        const float z = matvec_lds(Wr, wbuf) + bi;
        const float m_dt = (z > 0.f) ? DT_F : 0.f;
        float w = m_dt * z - DT_F * x;
        float y = x + w;

        // terms 2..KT
#pragma unroll
        for (int k = 2; k <= KT; ++k) {
            PUBLISH(wbuf, lane, w);
            const float v = matvec_lds(Wr, wbuf);
            w = (m_dt * v - DT_F * w) * (1.0f / (float)k);
            y += w;
        }
        x = y;
    }
}

extern "C" void kernel_launch(void* const* d_in, const int* in_sizes, int n_in,
                              void* d_out, int out_size, void* d_ws, size_t ws_size,
                              hipStream_t stream) {
    const float* x0 = (const float*)d_in[0];   // (256, 64) f32
    const float* W  = (const float*)d_in[1];   // (64, 64)  f32
    const float* b  = (const float*)d_in[2];   // (64,)     f32
    float* out = (float*)d_out;                // (256, 100, 64) f32

    // Problem shape is fixed (batch=256, dim=64). Derive batch from
    // in_sizes[0] when it is a plausible element count; clamp otherwise so a
    // bytes-vs-elements unit mismatch can never launch an OOB grid.
    int batch = in_sizes[0] / DD;
    if (batch <= 0 || batch > BATCH_MAX) batch = BATCH_MAX;
    abla_kernel<<<batch, DD, 0, stream>>>(x0, W, b, out);
}